// Round 9
// baseline (1273.342 us; speedup 1.0000x reference)
//
#include <hip/hip_runtime.h>

typedef __attribute__((ext_vector_type(8))) __bf16 bf16x8;
typedef __attribute__((ext_vector_type(4))) float f32x4;
typedef __attribute__((ext_vector_type(8))) unsigned short ushort8;

#define DSAMP 512
#define DIM   128
#define S1    ((size_t)16777216)   // one hi/lo array: 128 b * 2 c * 512 r * 128 B (swizzled)
#define REG5  16384                // one staged region: 128 rows * 128 B
#define NBPB  36                   // tiles per batch: 16 xy + 10 xx + 10 yy
#define PART_OFF  (4 * S1 + 2 * 262144)
#define FLAG_OFF  (PART_OFF + (size_t)128 * NBPB * 4)
#define WS_NEEDED (FLAG_OFF + 64)

// ---------------------------------------------------------------------------
// Dekker split helper: fp32 -> (hi, lo) bf16 pair, RNE.
// ---------------------------------------------------------------------------
__device__ __forceinline__ void split8(const float4& v0, const float4& v1,
                                       ushort8& hv, ushort8& lv) {
    float xs[8] = {v0.x, v0.y, v0.z, v0.w, v1.x, v1.y, v1.z, v1.w};
    #pragma unroll
    for (int e = 0; e < 8; ++e) {
        float xv = xs[e];
        unsigned ub = __float_as_uint(xv);
        unsigned hr = (ub + 0x7fffu + ((ub >> 16) & 1u)) >> 16;
        float hf = __uint_as_float(hr << 16);
        float rs = xv - hf;                       // exact residual
        unsigned ul = __float_as_uint(rs);
        unsigned lr = (ul + 0x7fffu + ((ul >> 16) & 1u)) >> 16;
        hv[e] = (unsigned short)hr;
        lv[e] = (unsigned short)lr;
    }
}

__device__ __forceinline__ void decode_s(int s, int& type, int& ti, int& tj,
                                         float& w, bool& diag) {
    if (s < 16) { type = 0; ti = s >> 2; tj = s & 3; w = 1.0f; diag = false; }
    else {
        int u = s - 16;
        type = 1 + (u >= 10);
        if (u >= 10) u -= 10;
        int i = (u >= 4) + (u >= 7) + (u >= 9);
        int off = (i == 1) ? 4 : (i == 2) ? 7 : (i == 3) ? 9 : 0;
        int j = u - off + i;
        ti = i; tj = j; diag = (i == j); w = diag ? -0.5f : -1.0f;
    }
}

// ---------------------------------------------------------------------------
// One 128x128 distance tile (the proven tile7 body): A-hi/B-hi async-DMA into
// 32 KB LDS, B-lo register-prefetched from global, 2-chunk K loop, cheap
// epilogue. Used by both the fused consumer and the standalone fallback.
// ---------------------------------------------------------------------------
__device__ __forceinline__
void tile_item(const char* __restrict__ ws, int b, int s,
               float* __restrict__ partials, int slot,
               char* smem, float* Pn, float* Qn, float* wred) {
    const int tid = threadIdx.x;
    int type, ti, tj; float w; bool diag;
    decode_s(s, type, ti, tj, w, diag);

    const char* Xhi = ws;
    const char* Yhi = ws + 2 * S1;
    const float* normX = (const float*)(ws + 4 * S1);
    const float* normY = normX + 65536;

    const char* Phi = (type == 2) ? Yhi : Xhi;
    const char* Qhi = (type == 1) ? Xhi : Yhi;
    const char* Qlo = Qhi + S1;
    const float* nP = (type == 2) ? normY : normX;
    const float* nQ = (type == 1) ? normX : normY;

    __syncthreads();   // smem/Pn reuse guard across items
    if (tid < 128) Pn[tid]       = nP[(size_t)b * 512 + ti * 128 + tid];
    else           Qn[tid - 128] = nQ[(size_t)b * 512 + tj * 128 + (tid - 128)];

    const int lane    = tid & 63;
    const int wv      = tid >> 6;
    const int rowHalf = (wv >> 1) * 64;
    const int colHalf = (wv & 1) * 64;
    const int fm      = lane & 15;
    const int kq      = lane >> 4;
    const int sw      = fm & 7;

    f32x4 acc[4][4];
    #pragma unroll
    for (int a2 = 0; a2 < 4; ++a2)
        #pragma unroll
        for (int b2 = 0; b2 < 4; ++b2)
            acc[a2][b2] = (f32x4){0.f, 0.f, 0.f, 0.f};

    for (int c = 0; c < 2; ++c) {
        if (c) __syncthreads();
        size_t chrow = (size_t)(b * 2 + c) * 512;
        {
            const char* srcs[2];
            srcs[0] = Phi + (chrow + (size_t)ti * 128) * 128;
            srcs[1] = Qhi + (chrow + (size_t)tj * 128) * 128;
            #pragma unroll
            for (int f = 0; f < 8; ++f) {
                int g = wv * 8 + f;
                int region = g >> 4;
                int sub    = g & 15;
                const char* gs = srcs[region] + sub * 1024 + lane * 16;
                char* ls = smem + (size_t)region * REG5 + sub * 1024 + lane * 16;
                __builtin_amdgcn_global_load_lds(
                    (const __attribute__((address_space(1))) void*)gs,
                    (__attribute__((address_space(3))) void*)ls, 16, 0, 0);
            }
        }
        bf16x8 bl[2][4];
        #pragma unroll
        for (int ks = 0; ks < 2; ++ks) {
            const int jx = ((ks * 4 + kq) ^ sw) * 16;
            #pragma unroll
            for (int b2 = 0; b2 < 4; ++b2) {
                size_t br = (size_t)(colHalf + b2 * 16 + fm);
                bl[ks][b2] = *(const bf16x8*)(Qlo + ((chrow + tj * 128 + br) << 7) + jx);
            }
        }
        __syncthreads();
        #pragma unroll
        for (int ks = 0; ks < 2; ++ks) {
            const int jx = ((ks * 4 + kq) ^ sw) * 16;
            bf16x8 ah[4], bh[4];
            #pragma unroll
            for (int a2 = 0; a2 < 4; ++a2) {
                int ar = rowHalf + a2 * 16 + fm;
                ah[a2] = *(const bf16x8*)(smem + ar * 128 + jx);
            }
            #pragma unroll
            for (int b2 = 0; b2 < 4; ++b2) {
                int br = colHalf + b2 * 16 + fm;
                bh[b2] = *(const bf16x8*)(smem + REG5 + br * 128 + jx);
            }
            #pragma unroll
            for (int a2 = 0; a2 < 4; ++a2)
                #pragma unroll
                for (int b2 = 0; b2 < 4; ++b2) {
                    acc[a2][b2] = __builtin_amdgcn_mfma_f32_16x16x32_bf16(ah[a2], bh[b2], acc[a2][b2], 0, 0, 0);
                    acc[a2][b2] = __builtin_amdgcn_mfma_f32_16x16x32_bf16(ah[a2], bl[ks][b2], acc[a2][b2], 0, 0, 0);
                }
        }
    }

    float Pr[16], Qc[4];
    #pragma unroll
    for (int a2 = 0; a2 < 4; ++a2)
        #pragma unroll
        for (int rg = 0; rg < 4; ++rg)
            Pr[a2 * 4 + rg] = Pn[rowHalf + a2 * 16 + kq * 4 + rg];
    #pragma unroll
    for (int b2 = 0; b2 < 4; ++b2) Qc[b2] = Qn[colHalf + b2 * 16 + fm];

    float lsum = 0.f;
    if (diag) {
        #pragma unroll
        for (int a2 = 0; a2 < 4; ++a2)
            #pragma unroll
            for (int b2 = 0; b2 < 4; ++b2)
                #pragma unroll
                for (int rg = 0; rg < 4; ++rg) {
                    float d2 = fmaf(-2.0f, acc[a2][b2][rg], Pr[a2 * 4 + rg] + Qc[b2]);
                    float v  = __builtin_amdgcn_sqrtf(fmaxf(d2, 0.0f));
                    if ((rowHalf + a2 * 16 + kq * 4 + rg) == (colHalf + b2 * 16 + fm)) v = 0.f;
                    lsum += v;
                }
    } else {
        #pragma unroll
        for (int a2 = 0; a2 < 4; ++a2)
            #pragma unroll
            for (int b2 = 0; b2 < 4; ++b2)
                #pragma unroll
                for (int rg = 0; rg < 4; ++rg) {
                    float d2 = fmaf(-2.0f, acc[a2][b2][rg], Pr[a2 * 4 + rg] + Qc[b2]);
                    lsum += __builtin_amdgcn_sqrtf(fmaxf(d2, 0.0f));
                }
    }
    #pragma unroll
    for (int off = 32; off > 0; off >>= 1) lsum += __shfl_down(lsum, off, 64);
    if (lane == 0) wred[wv] = lsum;
    __syncthreads();
    if (tid == 0)
        partials[slot] = (wred[0] + wred[1] + wred[2] + wred[3]) * w;
}

// ---------------------------------------------------------------------------
// Zero the producer-consumer flags (ws is poisoned 0xAA before every launch).
// ---------------------------------------------------------------------------
__global__ void zero_flags(int* __restrict__ flags) {
    if (threadIdx.x < 16) flags[threadIdx.x] = 0;
}

// ---------------------------------------------------------------------------
// FUSED cooperative kernel: 768 blocks (3/CU, all co-resident).
// Blocks 0..255: producers — presplit group-by-group (16 groups x 8 batches),
//   release-fence + atomicAdd(done[g]). Producer p serves batch class p&7.
// Blocks 256..767: consumers — 9 tile items each (batch class c&7, batch-
//   ascending), spin (relaxed agent atomic + s_sleep) until group ready.
// ---------------------------------------------------------------------------
__global__ __launch_bounds__(256, 3)
void mmd_fused(const float* __restrict__ x, const float* __restrict__ y,
               char* __restrict__ ws, float* __restrict__ partials,
               int* __restrict__ flags) {
    __shared__ __align__(16) char smem[2 * REG5];
    __shared__ float Pn[128];
    __shared__ float Qn[128];
    __shared__ float wred[4];

    const int tid = threadIdx.x;

    if (blockIdx.x < 256) {
        // ---------------- producer ----------------
        const int p   = blockIdx.x;
        const int jb  = tid & 7;
        const int cch = (tid >> 3) & 1;
        const int rhi = tid >> 4;
        char* hiX = ws;
        float* nG = (float*)(ws + 4 * S1);
        for (int g = 0; g < 16; ++g) {
            #pragma unroll
            for (int uu = 0; uu < 2; ++uu) {
                const int l    = (p & 7) * 64 + 2 * (p >> 3) + uu;   // 0..511
                const int b    = g * 8 + (l >> 6);                   // class = p&7
                const int rest = l & 63;
                const int input = rest >> 5;
                const int rs    = rest & 31;
                const int rb    = rs * 16 + rhi;
                const int ri    = b * 512 + rb;
                const float* src = (input ? y : x) + ((size_t)ri << 7) + cch * 64 + jb * 8;
                float4 v0 = ((const float4*)src)[0];
                float4 v1 = ((const float4*)src)[1];
                float s = v0.x * v0.x + v0.y * v0.y + v0.z * v0.z + v0.w * v0.w
                        + v1.x * v1.x + v1.y * v1.y + v1.z * v1.z + v1.w * v1.w;
                #pragma unroll
                for (int o = 8; o > 0; o >>= 1) s += __shfl_down(s, o, 16);
                ushort8 hv, lv;
                split8(v0, v1, hv, lv);
                char* hi = hiX + (size_t)input * 2 * S1;
                size_t off = ((size_t)(b * 2 + cch) * 512 + rb) * 128
                           + (size_t)((jb ^ (rb & 7)) * 16);
                *(ushort8*)(hi + off)      = hv;
                *(ushort8*)(hi + S1 + off) = lv;
                if ((tid & 15) == 0) nG[(size_t)input * 65536 + ri] = s;
            }
            __threadfence();          // each thread's stores visible device-wide
            __syncthreads();          // all threads fenced
            if (tid == 0) atomicAdd(&flags[g], 1);
        }
        return;
    }

    // ---------------- consumer ----------------
    const int c = blockIdx.x - 256;   // 0..511
    const int klass = c & 7;
    const int rc    = c >> 3;         // 0..63
    int kdone = -1;
    for (int j = 0; j < 9; ++j) {
        const int idx = rc + 64 * j;          // 0..575
        const int k   = idx / 36;             // batch rank 0..15 == group
        const int s   = idx - k * 36;
        const int b   = klass + 8 * k;
        if (k > kdone) {
            if (tid == 0) {
                while (__hip_atomic_load(flags + k, __ATOMIC_RELAXED,
                                         __HIP_MEMORY_SCOPE_AGENT) < 256)
                    __builtin_amdgcn_s_sleep(2);
            }
            __syncthreads();
            __threadfence();          // acquire: invalidate stale cached lines
            kdone = k;
        }
        tile_item(ws, b, s, partials, c * 9 + j, smem, Pn, Qn, wred);
    }
}

// ---------------------------------------------------------------------------
// Standalone two-kernel path (R7, proven) — used if cooperative launch fails.
// ---------------------------------------------------------------------------
__global__ __launch_bounds__(256)
void presplit5(const float* __restrict__ x, const float* __restrict__ y,
               char* __restrict__ ws) {
    const size_t t = (size_t)blockIdx.x * 256 + threadIdx.x;
    const int jb = (int)(t & 7);
    const int c  = (int)((t >> 3) & 1);
    const int r  = (int)(t >> 4);
    const int input = r >> 16;
    const int ri    = r & 65535;

    const float* src = (input ? y : x) + ((size_t)ri << 7) + c * 64 + jb * 8;
    float4 v0 = ((const float4*)src)[0];
    float4 v1 = ((const float4*)src)[1];
    float s = v0.x * v0.x + v0.y * v0.y + v0.z * v0.z + v0.w * v0.w
            + v1.x * v1.x + v1.y * v1.y + v1.z * v1.z + v1.w * v1.w;
    #pragma unroll
    for (int o = 8; o > 0; o >>= 1) s += __shfl_down(s, o, 16);
    ushort8 hv, lv;
    split8(v0, v1, hv, lv);
    const int b  = ri >> 9;
    const int rb = ri & 511;
    char* hi = ws + (size_t)input * 2 * S1;
    size_t off = ((size_t)(b * 2 + c) * 512 + rb) * 128
               + (size_t)((jb ^ (rb & 7)) * 16);
    *(ushort8*)(hi + off)      = hv;
    *(ushort8*)(hi + S1 + off) = lv;
    if ((t & 15) == 0) {
        float* nG = (float*)(ws + 4 * S1) + (size_t)input * 65536;
        nG[ri] = s;
    }
}

__global__ __launch_bounds__(256, 3)
void mmd_tile7k(const char* __restrict__ ws, float* __restrict__ partials) {
    __shared__ __align__(16) char smem[2 * REG5];
    __shared__ float Pn[128];
    __shared__ float Qn[128];
    __shared__ float wred[4];
    const int xcd = blockIdx.x & 7;
    const int seq = blockIdx.x >> 3;
    const int b   = xcd + 8 * (seq / NBPB);
    const int s   = seq % NBPB;
    tile_item(ws, b, s, partials, blockIdx.x, smem, Pn, Qn, wred);
}

// ---------------------------------------------------------------------------
// Last-resort fallback (in-kernel conversion) if ws_size too small.
// ---------------------------------------------------------------------------
__global__ __launch_bounds__(256, 2)
void mmd_tile_fallback(const float* __restrict__ x, const float* __restrict__ y,
                       float* __restrict__ partials) {
    __shared__ __align__(16) char smem[4 * 128 * 144];
    __shared__ float Pn[128];
    __shared__ float Qn[128];
    __shared__ float wred[4];

    char* Ah = smem;
    char* Al = smem + 1 * 128 * 144;
    char* Bh = smem + 2 * 128 * 144;
    char* Bl = smem + 3 * 128 * 144;

    const int tid  = threadIdx.x;
    const int bid  = blockIdx.x;
    const int tj   = bid & 3;
    const int ti   = (bid >> 2) & 3;
    const int type = (bid >> 4) % 3;
    const int b    = bid / 48;

    const float* Xb = x + (size_t)b * DSAMP * DIM;
    const float* Yb = y + (size_t)b * DSAMP * DIM;
    const float* Pp; const float* Qp; float w;
    if (type == 0)      { Pp = Xb; Qp = Yb; w = 1.0f;  }
    else if (type == 1) { Pp = Xb; Qp = Xb; w = -0.5f; }
    else                { Pp = Yb; Qp = Yb; w = -0.5f; }
    Pp += (size_t)ti * 128 * DIM;
    Qp += (size_t)tj * 128 * DIM;

    {
        const float* rp = (tid < 128) ? (Pp + (size_t)tid * DIM)
                                      : (Qp + (size_t)(tid - 128) * DIM);
        float s = 0.f;
        #pragma unroll
        for (int k4 = 0; k4 < 32; ++k4) {
            float4 v = ((const float4*)rp)[k4];
            s += v.x * v.x + v.y * v.y + v.z * v.z + v.w * v.w;
        }
        if (tid < 128) Pn[tid] = s; else Qn[tid - 128] = s;
    }

    const int lane    = tid & 63;
    const int wv      = tid >> 6;
    const int rowHalf = (wv >> 1) * 64;
    const int colHalf = (wv & 1) * 64;
    const int fm      = lane & 15;
    const int kq      = lane >> 4;

    f32x4 acc[4][4];
    #pragma unroll
    for (int a2 = 0; a2 < 4; ++a2)
        #pragma unroll
        for (int b2 = 0; b2 < 4; ++b2)
            acc[a2][b2] = (f32x4){0.f, 0.f, 0.f, 0.f};

    for (int c = 0; c < 2; ++c) {
        if (c) __syncthreads();
        #pragma unroll
        for (int side = 0; side < 2; ++side) {
            const float* sp = side ? Qp : Pp;
            char* dh = side ? Bh : Ah;
            char* dl = side ? Bl : Al;
            #pragma unroll
            for (int it = 0; it < 4; ++it) {
                int u  = it * 256 + tid;
                int r  = u >> 3;
                int c8 = u & 7;
                const float* g = sp + (size_t)r * DIM + c * 64 + c8 * 8;
                float4 v0 = ((const float4*)g)[0];
                float4 v1 = ((const float4*)g)[1];
                ushort8 hv, lv;
                split8(v0, v1, hv, lv);
                *(ushort8*)(dh + r * 144 + c8 * 16) = hv;
                *(ushort8*)(dl + r * 144 + c8 * 16) = lv;
            }
        }
        __syncthreads();
        #pragma unroll
        for (int ks = 0; ks < 2; ++ks) {
            const int kb2 = (ks * 32 + kq * 8) * 2;
            bf16x8 ah[4], al[4], bh[4], bl[4];
            #pragma unroll
            for (int a2 = 0; a2 < 4; ++a2) {
                int ar = rowHalf + a2 * 16 + fm;
                ah[a2] = *(const bf16x8*)(Ah + ar * 144 + kb2);
                al[a2] = *(const bf16x8*)(Al + ar * 144 + kb2);
            }
            #pragma unroll
            for (int b2 = 0; b2 < 4; ++b2) {
                int br = colHalf + b2 * 16 + fm;
                bh[b2] = *(const bf16x8*)(Bh + br * 144 + kb2);
                bl[b2] = *(const bf16x8*)(Bl + br * 144 + kb2);
            }
            #pragma unroll
            for (int a2 = 0; a2 < 4; ++a2)
                #pragma unroll
                for (int b2 = 0; b2 < 4; ++b2) {
                    acc[a2][b2] = __builtin_amdgcn_mfma_f32_16x16x32_bf16(ah[a2], bh[b2], acc[a2][b2], 0, 0, 0);
                    acc[a2][b2] = __builtin_amdgcn_mfma_f32_16x16x32_bf16(ah[a2], bl[b2], acc[a2][b2], 0, 0, 0);
                    acc[a2][b2] = __builtin_amdgcn_mfma_f32_16x16x32_bf16(al[a2], bh[b2], acc[a2][b2], 0, 0, 0);
                }
        }
    }

    const bool selfm = (type != 0) && (ti == tj);
    float lsum = 0.f;
    #pragma unroll
    for (int a2 = 0; a2 < 4; ++a2) {
        int ib = rowHalf + a2 * 16 + kq * 4;
        #pragma unroll
        for (int b2 = 0; b2 < 4; ++b2) {
            int j = colHalf + b2 * 16 + fm;
            float qn = Qn[j];
            #pragma unroll
            for (int rg = 0; rg < 4; ++rg) {
                int i = ib + rg;
                float d2 = Pn[i] + qn - 2.0f * acc[a2][b2][rg];
                if (d2 > 0.f && !(selfm && i == j)) lsum += sqrtf(d2);
            }
        }
    }
    #pragma unroll
    for (int off = 32; off > 0; off >>= 1) lsum += __shfl_down(lsum, off, 64);
    if (lane == 0) wred[wv] = lsum;
    __syncthreads();
    if (tid == 0)
        partials[bid] = (wred[0] + wred[1] + wred[2] + wred[3]) * w;
}

__global__ __launch_bounds__(256)
void mmd_finalize_kernel(const float* __restrict__ partials, int n,
                         float* __restrict__ out, double scale) {
    __shared__ double sh[256];
    double s = 0.0;
    for (int i = threadIdx.x; i < n; i += 256) s += (double)partials[i];
    sh[threadIdx.x] = s;
    __syncthreads();
    for (int off = 128; off > 0; off >>= 1) {
        if ((int)threadIdx.x < off) sh[threadIdx.x] += sh[threadIdx.x + off];
        __syncthreads();
    }
    if (threadIdx.x == 0) out[0] = (float)(sh[0] * scale);
}

extern "C" void kernel_launch(void* const* d_in, const int* in_sizes, int n_in,
                              void* d_out, int out_size, void* d_ws, size_t ws_size,
                              hipStream_t stream) {
    const float* x = (const float*)d_in[0];
    const float* y = (const float*)d_in[1];
    float* out = (float*)d_out;

    const int n = in_sizes[0];
    const int B = n / (DSAMP * DIM);       // 128
    const double scale = 1.0 / ((double)B * (double)DSAMP * (double)DSAMP);

    if (ws_size >= WS_NEEDED && B == 128) {
        char* ws = (char*)d_ws;
        float* partials = (float*)(ws + PART_OFF);
        int* flags = (int*)(ws + FLAG_OFF);
        const int nblocks = B * NBPB;      // 4608

        zero_flags<<<dim3(1), dim3(64), 0, stream>>>(flags);
        void* kargs[] = { (void*)&x, (void*)&y, (void*)&ws, (void*)&partials, (void*)&flags };
        hipError_t e = hipLaunchCooperativeKernel((const void*)mmd_fused,
                                                  dim3(768), dim3(256), kargs, 0, stream);
        if (e != hipSuccess) {
            // proven two-kernel path (R7)
            presplit5<<<dim3(8192), dim3(256), 0, stream>>>(x, y, ws);
            mmd_tile7k<<<dim3(nblocks), dim3(256), 0, stream>>>(ws, partials);
        }
        mmd_finalize_kernel<<<dim3(1), dim3(256), 0, stream>>>(partials, nblocks, out, scale);
    } else if (ws_size >= WS_NEEDED) {
        char* ws = (char*)d_ws;
        float* partials = (float*)(ws + PART_OFF);
        const int nblocks = B * NBPB;
        presplit5<<<dim3((2 * n / 8) / 256), dim3(256), 0, stream>>>(x, y, ws);
        mmd_tile7k<<<dim3(nblocks), dim3(256), 0, stream>>>(ws, partials);
        mmd_finalize_kernel<<<dim3(1), dim3(256), 0, stream>>>(partials, nblocks, out, scale);
    } else {
        float* partials = (float*)d_ws;
        const int nblocks = B * 48;
        mmd_tile_fallback<<<dim3(nblocks), dim3(256), 0, stream>>>(x, y, partials);
        mmd_finalize_kernel<<<dim3(1), dim3(256), 0, stream>>>(partials, nblocks, out, scale);
    }
}

// Round 10
// 132.832 us; speedup vs baseline: 9.5861x; 9.5861x over previous
//
#include <hip/hip_runtime.h>

typedef __attribute__((ext_vector_type(8))) __bf16 bf16x8;
typedef __attribute__((ext_vector_type(4))) float f32x4;
typedef __attribute__((ext_vector_type(8))) unsigned short ushort8;

#define DSAMP 512
#define DIM   128
#define S1    ((size_t)16777216)   // one hi array: 128 b * 2 c * 512 r * 128 B (swizzled)
#define REG5  16384                // one staged region: 128 rows * 128 B
#define NBPB  36                   // tiles per batch: 16 xy + 10 xx + 10 yy
#define NORM_OFF (2 * S1)
#define PART_OFF (2 * S1 + 524288)
#define WS_NEEDED (PART_OFF + (size_t)128 * NBPB * 4)

// ---------------------------------------------------------------------------
// Pass 1 v6: bf16-hi ONLY (loss structure cancels first-order + quadratic
// rounding between cross and self terms; exact fp32 norms carry the rest).
// One thread = 8 consecutive floats = one 16-B swizzled block. 128 MB traffic.
// ---------------------------------------------------------------------------
__global__ __launch_bounds__(256)
void presplit6(const float* __restrict__ x, const float* __restrict__ y,
               char* __restrict__ ws) {
    const size_t t = (size_t)blockIdx.x * 256 + threadIdx.x;   // 0..2M-1
    const int jb = (int)(t & 7);          // 16B block within chunk row
    const int c  = (int)((t >> 3) & 1);   // k-chunk 0/1
    const int r  = (int)(t >> 4);         // global row 0..131071
    const int input = r >> 16;            // 0=x, 1=y
    const int ri    = r & 65535;

    const float* src = (input ? y : x) + ((size_t)ri << 7) + c * 64 + jb * 8;
    float4 v0 = ((const float4*)src)[0];
    float4 v1 = ((const float4*)src)[1];

    // exact fp32 row norm (16 lanes per row, aligned group)
    float s = v0.x * v0.x + v0.y * v0.y + v0.z * v0.z + v0.w * v0.w
            + v1.x * v1.x + v1.y * v1.y + v1.z * v1.z + v1.w * v1.w;
    #pragma unroll
    for (int o = 8; o > 0; o >>= 1) s += __shfl_down(s, o, 16);

    float xs[8] = {v0.x, v0.y, v0.z, v0.w, v1.x, v1.y, v1.z, v1.w};
    ushort8 hv;
    #pragma unroll
    for (int e = 0; e < 8; ++e) {
        unsigned ub = __float_as_uint(xs[e]);
        hv[e] = (unsigned short)((ub + 0x7fffu + ((ub >> 16) & 1u)) >> 16);  // RNE
    }

    const int b  = ri >> 9;
    const int rb = ri & 511;
    char* hi = ws + (size_t)input * S1;
    size_t off = ((size_t)(b * 2 + c) * 512 + rb) * 128
               + (size_t)((jb ^ (rb & 7)) * 16);
    *(ushort8*)(hi + off) = hv;

    if ((t & 15) == 0) {
        float* nG = (float*)(ws + NORM_OFF) + (size_t)input * 65536;
        nG[ri] = s;
    }
}

// ---------------------------------------------------------------------------
// Pass 2 v9: 128x128 tile, bf16-hi MFMA only. A-hi/B-hi async-DMA into 32 KB
// LDS; 4 blocks/CU (no bl registers held -> fits the 128-reg cap that R6
// spilled at). Upper-triangle tiling + XCD-aware batch placement.
// ---------------------------------------------------------------------------
__global__ __launch_bounds__(256, 4)
void mmd_tile9(const char* __restrict__ ws, float* __restrict__ partials) {
    __shared__ __align__(16) char smem[2 * REG5];   // Ah, Bh (32768 B)
    __shared__ float Pn[128];
    __shared__ float Qn[128];
    __shared__ float wred[4];

    const int tid = threadIdx.x;
    const int xcd = blockIdx.x & 7;
    const int seq = blockIdx.x >> 3;
    const int b   = xcd + 8 * (seq / NBPB);
    const int s   = seq % NBPB;

    int type, ti, tj; float w; bool diag;
    if (s < 16) { type = 0; ti = s >> 2; tj = s & 3; w = 1.0f; diag = false; }
    else {
        int u = s - 16;
        type = 1 + (u >= 10);
        if (u >= 10) u -= 10;
        int i = (u >= 4) + (u >= 7) + (u >= 9);
        int off = (i == 1) ? 4 : (i == 2) ? 7 : (i == 3) ? 9 : 0;
        int j = u - off + i;
        ti = i; tj = j; diag = (i == j); w = diag ? -0.5f : -1.0f;
    }

    const char* Xhi = ws;
    const char* Yhi = ws + S1;
    const float* normX = (const float*)(ws + NORM_OFF);
    const float* normY = normX + 65536;

    const char* Phi = (type == 2) ? Yhi : Xhi;
    const char* Qhi = (type == 1) ? Xhi : Yhi;
    const float* nP = (type == 2) ? normY : normX;
    const float* nQ = (type == 1) ? normX : normY;

    if (tid < 128) Pn[tid]       = nP[(size_t)b * 512 + ti * 128 + tid];
    else           Qn[tid - 128] = nQ[(size_t)b * 512 + tj * 128 + (tid - 128)];

    const int lane    = tid & 63;
    const int wv      = tid >> 6;
    const int rowHalf = (wv >> 1) * 64;
    const int colHalf = (wv & 1) * 64;
    const int fm      = lane & 15;
    const int kq      = lane >> 4;
    const int sw      = fm & 7;        // swizzle key (row & 7 == fm & 7)

    f32x4 acc[4][4];
    #pragma unroll
    for (int a2 = 0; a2 < 4; ++a2)
        #pragma unroll
        for (int b2 = 0; b2 < 4; ++b2)
            acc[a2][b2] = (f32x4){0.f, 0.f, 0.f, 0.f};

    for (int c = 0; c < 2; ++c) {
        if (c) __syncthreads();
        size_t chrow = (size_t)(b * 2 + c) * 512;
        {
            const char* srcs[2];
            srcs[0] = Phi + (chrow + (size_t)ti * 128) * 128;
            srcs[1] = Qhi + (chrow + (size_t)tj * 128) * 128;
            #pragma unroll
            for (int f = 0; f < 8; ++f) {
                int g = wv * 8 + f;            // 0..31
                int region = g >> 4;
                int sub    = g & 15;
                const char* gs = srcs[region] + sub * 1024 + lane * 16;
                char* ls = smem + (size_t)region * REG5 + sub * 1024 + lane * 16;
                __builtin_amdgcn_global_load_lds(
                    (const __attribute__((address_space(1))) void*)gs,
                    (__attribute__((address_space(3))) void*)ls, 16, 0, 0);
            }
        }
        __syncthreads();
        #pragma unroll
        for (int ks = 0; ks < 2; ++ks) {
            const int jx = ((ks * 4 + kq) ^ sw) * 16;
            bf16x8 ah[4], bh[4];
            #pragma unroll
            for (int a2 = 0; a2 < 4; ++a2) {
                int ar = rowHalf + a2 * 16 + fm;
                ah[a2] = *(const bf16x8*)(smem + ar * 128 + jx);
            }
            #pragma unroll
            for (int b2 = 0; b2 < 4; ++b2) {
                int br = colHalf + b2 * 16 + fm;
                bh[b2] = *(const bf16x8*)(smem + REG5 + br * 128 + jx);
            }
            #pragma unroll
            for (int a2 = 0; a2 < 4; ++a2)
                #pragma unroll
                for (int b2 = 0; b2 < 4; ++b2)
                    acc[a2][b2] = __builtin_amdgcn_mfma_f32_16x16x32_bf16(ah[a2], bh[b2], acc[a2][b2], 0, 0, 0);
        }
    }

    // ---- epilogue: d2 = Pn + Qn - 2g -> guarded sqrt -> reduce ----
    float Pr[16], Qc[4];
    #pragma unroll
    for (int a2 = 0; a2 < 4; ++a2)
        #pragma unroll
        for (int rg = 0; rg < 4; ++rg)
            Pr[a2 * 4 + rg] = Pn[rowHalf + a2 * 16 + kq * 4 + rg];
    #pragma unroll
    for (int b2 = 0; b2 < 4; ++b2) Qc[b2] = Qn[colHalf + b2 * 16 + fm];

    float lsum = 0.f;
    if (diag) {
        #pragma unroll
        for (int a2 = 0; a2 < 4; ++a2)
            #pragma unroll
            for (int b2 = 0; b2 < 4; ++b2)
                #pragma unroll
                for (int rg = 0; rg < 4; ++rg) {
                    float d2 = fmaf(-2.0f, acc[a2][b2][rg], Pr[a2 * 4 + rg] + Qc[b2]);
                    float v  = __builtin_amdgcn_sqrtf(fmaxf(d2, 0.0f));
                    if ((rowHalf + a2 * 16 + kq * 4 + rg) == (colHalf + b2 * 16 + fm)) v = 0.f;
                    lsum += v;
                }
    } else {
        #pragma unroll
        for (int a2 = 0; a2 < 4; ++a2)
            #pragma unroll
            for (int b2 = 0; b2 < 4; ++b2)
                #pragma unroll
                for (int rg = 0; rg < 4; ++rg) {
                    float d2 = fmaf(-2.0f, acc[a2][b2][rg], Pr[a2 * 4 + rg] + Qc[b2]);
                    lsum += __builtin_amdgcn_sqrtf(fmaxf(d2, 0.0f));
                }
    }
    #pragma unroll
    for (int off = 32; off > 0; off >>= 1) lsum += __shfl_down(lsum, off, 64);
    if (lane == 0) wred[wv] = lsum;
    __syncthreads();
    if (tid == 0)
        partials[blockIdx.x] = (wred[0] + wred[1] + wred[2] + wred[3]) * w;
}

// ---------------------------------------------------------------------------
// Fallback (in-kernel 3-term conversion, full 48 tiles/batch) if ws too small.
// ---------------------------------------------------------------------------
__global__ __launch_bounds__(256, 2)
void mmd_tile_fallback(const float* __restrict__ x, const float* __restrict__ y,
                       float* __restrict__ partials) {
    __shared__ __align__(16) char smem[4 * 128 * 144];
    __shared__ float Pn[128];
    __shared__ float Qn[128];
    __shared__ float wred[4];

    char* Ah = smem;
    char* Al = smem + 1 * 128 * 144;
    char* Bh = smem + 2 * 128 * 144;
    char* Bl = smem + 3 * 128 * 144;

    const int tid  = threadIdx.x;
    const int bid  = blockIdx.x;
    const int tj   = bid & 3;
    const int ti   = (bid >> 2) & 3;
    const int type = (bid >> 4) % 3;
    const int b    = bid / 48;

    const float* Xb = x + (size_t)b * DSAMP * DIM;
    const float* Yb = y + (size_t)b * DSAMP * DIM;
    const float* Pp; const float* Qp; float w;
    if (type == 0)      { Pp = Xb; Qp = Yb; w = 1.0f;  }
    else if (type == 1) { Pp = Xb; Qp = Xb; w = -0.5f; }
    else                { Pp = Yb; Qp = Yb; w = -0.5f; }
    Pp += (size_t)ti * 128 * DIM;
    Qp += (size_t)tj * 128 * DIM;

    {
        const float* rp = (tid < 128) ? (Pp + (size_t)tid * DIM)
                                      : (Qp + (size_t)(tid - 128) * DIM);
        float s = 0.f;
        #pragma unroll
        for (int k4 = 0; k4 < 32; ++k4) {
            float4 v = ((const float4*)rp)[k4];
            s += v.x * v.x + v.y * v.y + v.z * v.z + v.w * v.w;
        }
        if (tid < 128) Pn[tid] = s; else Qn[tid - 128] = s;
    }

    const int lane    = tid & 63;
    const int wv      = tid >> 6;
    const int rowHalf = (wv >> 1) * 64;
    const int colHalf = (wv & 1) * 64;
    const int fm      = lane & 15;
    const int kq      = lane >> 4;

    f32x4 acc[4][4];
    #pragma unroll
    for (int a2 = 0; a2 < 4; ++a2)
        #pragma unroll
        for (int b2 = 0; b2 < 4; ++b2)
            acc[a2][b2] = (f32x4){0.f, 0.f, 0.f, 0.f};

    for (int c = 0; c < 2; ++c) {
        if (c) __syncthreads();
        #pragma unroll
        for (int side = 0; side < 2; ++side) {
            const float* sp = side ? Qp : Pp;
            char* dh = side ? Bh : Ah;
            char* dl = side ? Bl : Al;
            #pragma unroll
            for (int it = 0; it < 4; ++it) {
                int u  = it * 256 + tid;
                int r  = u >> 3;
                int c8 = u & 7;
                const float* g = sp + (size_t)r * DIM + c * 64 + c8 * 8;
                float4 v0 = ((const float4*)g)[0];
                float4 v1 = ((const float4*)g)[1];
                float xs[8] = {v0.x, v0.y, v0.z, v0.w, v1.x, v1.y, v1.z, v1.w};
                ushort8 hv, lv;
                #pragma unroll
                for (int e = 0; e < 8; ++e) {
                    float xv = xs[e];
                    unsigned ub = __float_as_uint(xv);
                    unsigned hr = (ub + 0x7fffu + ((ub >> 16) & 1u)) >> 16;
                    float hf = __uint_as_float(hr << 16);
                    float rs = xv - hf;
                    unsigned ul = __float_as_uint(rs);
                    unsigned lr = (ul + 0x7fffu + ((ul >> 16) & 1u)) >> 16;
                    hv[e] = (unsigned short)hr;
                    lv[e] = (unsigned short)lr;
                }
                *(ushort8*)(dh + r * 144 + c8 * 16) = hv;
                *(ushort8*)(dl + r * 144 + c8 * 16) = lv;
            }
        }
        __syncthreads();
        #pragma unroll
        for (int ks = 0; ks < 2; ++ks) {
            const int kb2 = (ks * 32 + kq * 8) * 2;
            bf16x8 ah[4], al[4], bh[4], bl[4];
            #pragma unroll
            for (int a2 = 0; a2 < 4; ++a2) {
                int ar = rowHalf + a2 * 16 + fm;
                ah[a2] = *(const bf16x8*)(Ah + ar * 144 + kb2);
                al[a2] = *(const bf16x8*)(Al + ar * 144 + kb2);
            }
            #pragma unroll
            for (int b2 = 0; b2 < 4; ++b2) {
                int br = colHalf + b2 * 16 + fm;
                bh[b2] = *(const bf16x8*)(Bh + br * 144 + kb2);
                bl[b2] = *(const bf16x8*)(Bl + br * 144 + kb2);
            }
            #pragma unroll
            for (int a2 = 0; a2 < 4; ++a2)
                #pragma unroll
                for (int b2 = 0; b2 < 4; ++b2) {
                    acc[a2][b2] = __builtin_amdgcn_mfma_f32_16x16x32_bf16(ah[a2], bh[b2], acc[a2][b2], 0, 0, 0);
                    acc[a2][b2] = __builtin_amdgcn_mfma_f32_16x16x32_bf16(ah[a2], bl[b2], acc[a2][b2], 0, 0, 0);
                    acc[a2][b2] = __builtin_amdgcn_mfma_f32_16x16x32_bf16(al[a2], bh[b2], acc[a2][b2], 0, 0, 0);
                }
        }
    }

    const bool selfm = (type != 0) && (ti == tj);
    float lsum = 0.f;
    #pragma unroll
    for (int a2 = 0; a2 < 4; ++a2) {
        int ib = rowHalf + a2 * 16 + kq * 4;
        #pragma unroll
        for (int b2 = 0; b2 < 4; ++b2) {
            int j = colHalf + b2 * 16 + fm;
            float qn = Qn[j];
            #pragma unroll
            for (int rg = 0; rg < 4; ++rg) {
                int i = ib + rg;
                float d2 = Pn[i] + qn - 2.0f * acc[a2][b2][rg];
                if (d2 > 0.f && !(selfm && i == j)) lsum += sqrtf(d2);
            }
        }
    }
    #pragma unroll
    for (int off = 32; off > 0; off >>= 1) lsum += __shfl_down(lsum, off, 64);
    if (lane == 0) wred[wv] = lsum;
    __syncthreads();
    if (tid == 0)
        partials[bid] = (wred[0] + wred[1] + wred[2] + wred[3]) * w;
}

__global__ __launch_bounds__(256)
void mmd_finalize_kernel(const float* __restrict__ partials, int n,
                         float* __restrict__ out, double scale) {
    __shared__ double sh[256];
    double s = 0.0;
    for (int i = threadIdx.x; i < n; i += 256) s += (double)partials[i];
    sh[threadIdx.x] = s;
    __syncthreads();
    for (int off = 128; off > 0; off >>= 1) {
        if ((int)threadIdx.x < off) sh[threadIdx.x] += sh[threadIdx.x + off];
        __syncthreads();
    }
    if (threadIdx.x == 0) out[0] = (float)(sh[0] * scale);
}

extern "C" void kernel_launch(void* const* d_in, const int* in_sizes, int n_in,
                              void* d_out, int out_size, void* d_ws, size_t ws_size,
                              hipStream_t stream) {
    const float* x = (const float*)d_in[0];
    const float* y = (const float*)d_in[1];
    float* out = (float*)d_out;

    const int n = in_sizes[0];
    const int B = n / (DSAMP * DIM);       // 128
    const double scale = 1.0 / ((double)B * (double)DSAMP * (double)DSAMP);

    if (ws_size >= WS_NEEDED) {
        char* ws = (char*)d_ws;
        float* partials = (float*)(ws + PART_OFF);
        const int nblocks = B * NBPB;      // 4608
        presplit6<<<dim3((2 * n / 8) / 256), dim3(256), 0, stream>>>(x, y, ws);
        mmd_tile9<<<dim3(nblocks), dim3(256), 0, stream>>>(ws, partials);
        mmd_finalize_kernel<<<dim3(1), dim3(256), 0, stream>>>(partials, nblocks, out, scale);
    } else {
        float* partials = (float*)d_ws;
        const int nblocks = B * 48;
        mmd_tile_fallback<<<dim3(nblocks), dim3(256), 0, stream>>>(x, y, partials);
        mmd_finalize_kernel<<<dim3(1), dim3(256), 0, stream>>>(partials, nblocks, out, scale);
    }
}